// Round 6
// baseline (157.044 us; speedup 1.0000x reference)
//
#include <hip/hip_runtime.h>

namespace {
constexpr float kLrelu = 0.2f;
constexpr float kEps   = 1e-5f;
}

typedef short bf16x8 __attribute__((ext_vector_type(8)));
typedef float f32x4  __attribute__((ext_vector_type(4)));

// round-to-nearest-even f32 -> bf16 (inputs are finite)
static __device__ __forceinline__ unsigned f2bf(float x) {
  unsigned u = __float_as_uint(x);
  return (u + 0x7FFFu + ((u >> 16) & 1u)) >> 16;
}
static __device__ __forceinline__ unsigned packbf(float a, float b) {
  return f2bf(a) | (f2bf(b) << 16);
}

// Grouped conv as 64 x [256x512x2048] bf16-MFMA GEMM + per-channel stats.
// Block = (g, z-tile 64, m-tile 128), 256 threads = 4 waves, wave = 64z x 32m.
// Grid 1024 -> 4 resident blocks/CU (independent barrier domains for latency
// hiding; round-5 showed 2 blocks/CU = 20% occupancy starves the chain).
// Per K-chunk (BK=32 = 2 input channels): coalesced raw-patch staging (dbuf,
// depth-2 reg prefetch) -> row-gather (2x ds_read_b128, compile-time tap
// selects) -> bf16 B-tile -> 8 MFMA per wave.
// Writes raw conv output into d_out in FOLD layout: out[b][z][hp*4+oy][wp*4+ox].
__global__ __launch_bounds__(256, 4) void conv_mfma(
    const float* __restrict__ input,   // [32,128,64,64]
    const float* __restrict__ weight,  // [16384, 2048]  (k = nc*16 + ky*4 + kx)
    float* __restrict__ out,           // [32,256,32,32]
    float* __restrict__ stats)         // [16384][2] (sum, sumsq)
{
  // raw patch tiles: 16 patches (8 b x 2 nc) x 64 floats, row-XOR swizzle:
  //   addr(fl) = pl*64 + ((py ^ bl)<<3) + px
  __shared__ __align__(16) float raw0[16 * 64];   // 4 KB
  __shared__ __align__(16) float raw1[16 * 64];   // 4 KB
  // GEMM tiles, row = 64B (32 bf16), 16B-granule XOR swizzle (gk ^ ((row>>1)&3))
  __shared__ __align__(16) char Bs[128 * 64];     // 8 KB
  __shared__ __align__(16) char As[64 * 64];      // 4 KB

  const int bid  = blockIdx.x;
  const int orig = (bid & 7) * 128 + (bid >> 3);  // XCD-chunked (1024 % 8 == 0)
  const int g    = orig >> 4;
  const int zt   = (orig >> 2) & 3;
  const int mt   = orig & 3;
  const int hp = g >> 3, wp = g & 7;
  const int z0 = zt * 64;
  const int m0 = mt * 128;

  const int tid  = threadIdx.x;
  const int lane = tid & 63;
  const int w    = tid >> 6;                      // wave 0..3, m-range = m0 + w*32
  const int llo  = lane & 15, lhi = lane >> 4;

  // -------- raw staging: one float4/thread/chunk (16 patches x 16 float4)
  const int pl_s  = tid >> 4;                     // patch 0..15
  const int f4    = tid & 15;
  const int bl_s  = pl_s >> 1;                    // b local 0..7
  const int ncs_s = pl_s & 1;
  const int py_s  = f4 >> 1, h_s = f4 & 1;
  const float* const gsrc = input
      + ((size_t)(mt * 8 + bl_s) * 128 + ncs_s) * 4096
      + (hp * 8 + py_s) * 64 + wp * 8 + (h_s << 2);   // + ck*2*4096 per chunk
  const int roff = pl_s * 64 + ((py_s ^ bl_s) << 3) + (h_s << 2);
  float* const rd0 = raw0 + roff;
  float* const rd1 = raw1 + roff;

  // -------- weight staging: rows az0=tid>>3 and az0+32; kq=tid&7 (k=kq*4..+3)
  const int az0 = tid >> 3;
  const int kq  = tid & 7;
  const float* const wsrc =
      weight + ((size_t)(g * 256 + z0 + az0)) * 2048 + kq * 4;  // 2nd: +65536
  const int aswz = (az0 >> 1) & 3;   // ((az0+32)>>1)&3 is identical
  char* const ad0 = As + az0 * 64 + (((kq >> 1) ^ aswz) << 4) + ((kq & 1) << 3);
  char* const ad1 = ad0 + 32 * 64;

  // -------- row-gather: thread -> (ncs=tid>>7, bl, oy, ky)
  const int rr   = tid & 127;
  const int bl_g = rr >> 4;                       // 0..7
  const int oy_g = (rr >> 2) & 3;
  const int ky_g = rr & 3;
  const int ncs  = tid >> 7;
  const int iy   = 2 * oy_g - 1 + ky_g;
  const unsigned rowm = ((unsigned)iy < 8u) ? 0xFFFFFFFFu : 0u;
  const int iyc  = iy < 0 ? 0 : (iy > 7 ? 7 : iy);
  const int gro  = (bl_g * 2 + ncs) * 64 + ((iyc ^ bl_g) << 3);
  // B-write dsts: ml = bl*16+oy*4+ox, byte col = ncs*32 + ky*8
  char* bwd[4];
#pragma unroll
  for (int ox = 0; ox < 4; ++ox) {
    const int ml = bl_g * 16 + oy_g * 4 + ox;
    const int gk = ncs * 2 + (ky_g >> 1);
    bwd[ox] = Bs + ml * 64 + ((gk ^ ((ml >> 1) & 3)) << 4) + ((ky_g & 1) << 3);
  }

  // -------- fragment read pointers
  const char* afp[4];
#pragma unroll
  for (int zf = 0; zf < 4; ++zf) {
    const int ar = zf * 16 + llo;
    afp[zf] = As + ar * 64 + ((lhi ^ ((ar >> 1) & 3)) << 4);
  }
  const char* bfp[2];
#pragma unroll
  for (int mf = 0; mf < 2; ++mf) {
    const int mr = w * 32 + mf * 16 + llo;        // local row in Bs
    bfp[mf] = Bs + mr * 64 + ((lhi ^ ((mr >> 1) & 3)) << 4);
  }

  f32x4 acc[4][2] = {};

  // tap selects: row[0..7] = r0.xyzw r1.xyzw; tap(ox,kx) = row[2ox-1+kx]
  uint2 ub[4];
  auto gather = [&](const float* rw) {
    const float4 r0 = *(const float4*)(rw + gro);
    const float4 r1 = *(const float4*)(rw + gro + 4);
    uint2 t;
    t.x = packbf(0.f, r0.x) & rowm;  t.y = packbf(r0.y, r0.z) & rowm;  ub[0] = t;
    t.x = packbf(r0.y, r0.z) & rowm; t.y = packbf(r0.w, r1.x) & rowm;  ub[1] = t;
    t.x = packbf(r0.w, r1.x) & rowm; t.y = packbf(r1.y, r1.z) & rowm;  ub[2] = t;
    t.x = packbf(r1.y, r1.z) & rowm; t.y = packbf(r1.w, 0.f) & rowm;   ub[3] = t;
  };
  auto writeB = [&]() {
#pragma unroll
    for (int ox = 0; ox < 4; ++ox) *(uint2*)bwd[ox] = ub[ox];
  };
  auto domfma = [&]() {
    bf16x8 bfv[2];
#pragma unroll
    for (int mf = 0; mf < 2; ++mf) bfv[mf] = *(const bf16x8*)bfp[mf];
#pragma unroll
    for (int zf = 0; zf < 4; ++zf) {
      const bf16x8 af = *(const bf16x8*)afp[zf];
#pragma unroll
      for (int mf = 0; mf < 2; ++mf)
        acc[zf][mf] = __builtin_amdgcn_mfma_f32_16x16x32_bf16(af, bfv[mf], acc[zf][mf], 0, 0, 0);
    }
  };

  // -------- prologue: prefetch chunks 0,1; stage chunk 0 into raw0
  float4 ra  = *(const float4*)(gsrc);
  float4 rb  = *(const float4*)(gsrc + 8192);
  float4 wa0 = *(const float4*)(wsrc);
  float4 wa1 = *(const float4*)(wsrc + 65536);
  float4 wb0 = *(const float4*)(wsrc + 32);
  float4 wb1 = *(const float4*)(wsrc + 65536 + 32);
  *(float4*)rd0 = ra;
  __syncthreads();

  for (int ck = 0; ck < 64; ck += 2) {
    // ============ even chunk ck (gather raw0, stage ck+1 -> raw1) ============
    {
      gather(raw0);
      uint2 a0w, a1w;
      a0w.x = packbf(wa0.x, wa0.y); a0w.y = packbf(wa0.z, wa0.w);
      a1w.x = packbf(wa1.x, wa1.y); a1w.y = packbf(wa1.z, wa1.w);
      if (ck + 2 < 64) {
        ra  = *(const float4*)(gsrc + (size_t)(ck + 2) * 8192);
        wa0 = *(const float4*)(wsrc + (ck + 2) * 32);
        wa1 = *(const float4*)(wsrc + 65536 + (ck + 2) * 32);
      }
      __syncthreads();             // prev MFMAs + this gather done reading LDS
      *(uint2*)ad0 = a0w;
      *(uint2*)ad1 = a1w;
      writeB();
      *(float4*)rd1 = rb;          // stage chunk ck+1
      __syncthreads();
      domfma();
    }
    // ============ odd chunk ck+1 (gather raw1, stage ck+2 -> raw0) ===========
    {
      gather(raw1);
      uint2 a0w, a1w;
      a0w.x = packbf(wb0.x, wb0.y); a0w.y = packbf(wb0.z, wb0.w);
      a1w.x = packbf(wb1.x, wb1.y); a1w.y = packbf(wb1.z, wb1.w);
      if (ck + 3 < 64) {
        rb  = *(const float4*)(gsrc + (size_t)(ck + 3) * 8192);
        wb0 = *(const float4*)(wsrc + (ck + 3) * 32);
        wb1 = *(const float4*)(wsrc + 65536 + (ck + 3) * 32);
      }
      __syncthreads();
      *(uint2*)ad0 = a0w;
      *(uint2*)ad1 = a1w;
      writeB();
      if (ck + 2 < 64) *(float4*)rd0 = ra;   // stage chunk ck+2
      __syncthreads();
      domfma();
    }
  }

  // -------- per-channel stats (sum, sumsq) over the wave's 32 m
#pragma unroll
  for (int zf = 0; zf < 4; ++zf) {
    float s[4], ss[4];
#pragma unroll
    for (int r = 0; r < 4; ++r) {
      s[r]  = acc[zf][0][r] + acc[zf][1][r];
      ss[r] = acc[zf][0][r] * acc[zf][0][r] + acc[zf][1][r] * acc[zf][1][r];
    }
#pragma unroll
    for (int off = 1; off <= 8; off <<= 1) {
#pragma unroll
      for (int r = 0; r < 4; ++r) {
        s[r]  += __shfl_xor(s[r], off);
        ss[r] += __shfl_xor(ss[r], off);
      }
    }
    if (llo == 0) {
      const int ch = g * 256 + z0 + zf * 16 + lhi * 4;
#pragma unroll
      for (int r = 0; r < 4; ++r) {
        atomicAdd(&stats[2 * (ch + r)],     s[r]);
        atomicAdd(&stats[2 * (ch + r) + 1], ss[r]);
      }
    }
  }

  // -------- store raw conv to d_out in fold layout
#pragma unroll
  for (int zf = 0; zf < 4; ++zf) {
    const int zch = z0 + zf * 16 + lhi * 4;       // + r below
#pragma unroll
    for (int mf = 0; mf < 2; ++mf) {
      const int mm  = m0 + w * 32 + mf * 16 + llo;
      const int bb  = mm >> 4;
      const int o_y = (mm >> 2) & 3;
      const int o_x = mm & 3;
      float* op = out + (((size_t)bb * 256 + zch) * 32 + hp * 4 + o_y) * 32
                      + wp * 4 + o_x;
#pragma unroll
      for (int r = 0; r < 4; ++r) op[(size_t)r * 1024] = acc[zf][mf][r];
    }
  }
}

// Pass 2: in-place BatchNorm (batch stats) + LeakyReLU on the fold-layout buffer.
__global__ __launch_bounds__(256) void bn_lrelu(
    float* __restrict__ out,
    const float* __restrict__ stats,
    const float* __restrict__ gamma,
    const float* __restrict__ beta)
{
  size_t t = (size_t)blockIdx.x * blockDim.x + threadIdx.x;
  size_t o = t * 4;                    // float4 per thread
  int X0 = (int)(o & 31);
  int Y  = (int)((o >> 5) & 31);
  int z  = (int)((o >> 10) & 255);
  int ch = ((Y >> 2) * 8 + (X0 >> 2)) * 256 + z;  // (hp*8+wp)*256 + z
  float s  = stats[2 * ch];
  float ss = stats[2 * ch + 1];
  float mean = s * (1.f / 512.f);
  float var  = fmaf(-mean, mean, ss * (1.f / 512.f));
  float inv  = gamma[ch] * rsqrtf(var + kEps);
  float sh   = fmaf(-mean, inv, beta[ch]);
  float4 v = *(float4*)&out[o];
  float vv[4] = {v.x, v.y, v.z, v.w};
#pragma unroll
  for (int j = 0; j < 4; ++j) {
    float y = fmaf(vv[j], inv, sh);
    vv[j] = y > 0.f ? y : kLrelu * y;
  }
  *(float4*)&out[o] = make_float4(vv[0], vv[1], vv[2], vv[3]);
}

extern "C" void kernel_launch(void* const* d_in, const int* in_sizes, int n_in,
                              void* d_out, int out_size, void* d_ws, size_t ws_size,
                              hipStream_t stream) {
  const float* input  = (const float*)d_in[0];
  const float* weight = (const float*)d_in[1];
  const float* gamma  = (const float*)d_in[2];
  const float* beta   = (const float*)d_in[3];
  float* out   = (float*)d_out;
  float* stats = (float*)d_ws;  // 16384 * 2 floats = 128 KB

  (void)hipMemsetAsync(stats, 0, (size_t)16384 * 2 * sizeof(float), stream);

  conv_mfma<<<1024, 256, 0, stream>>>(input, weight, out, stats);

  int n4 = out_size / 4;               // 2,097,152 float4s
  bn_lrelu<<<(n4 + 255) / 256, 256, 0, stream>>>(out, stats, gamma, beta);
}

// Round 7
// 117.137 us; speedup vs baseline: 1.3407x; 1.3407x over previous
//
#include <hip/hip_runtime.h>

namespace {
constexpr float kLrelu = 0.2f;
constexpr float kEps   = 1e-5f;
}

typedef short bf16x8 __attribute__((ext_vector_type(8)));
typedef float f32x4  __attribute__((ext_vector_type(4)));

// LDS-only barrier: waits local ops, does NOT drain vmcnt -> global prefetch
// loads stay in flight across the barrier (T4; __syncthreads would emit
// s_waitcnt vmcnt(0) and expose full HBM latency every chunk).
#define LDS_BARRIER() asm volatile("s_waitcnt lgkmcnt(0)\n\ts_barrier" ::: "memory")

// round-to-nearest-even f32 -> bf16 (inputs are finite)
static __device__ __forceinline__ unsigned f2bf(float x) {
  unsigned u = __float_as_uint(x);
  return (u + 0x7FFFu + ((u >> 16) & 1u)) >> 16;
}
static __device__ __forceinline__ unsigned packbf(float a, float b) {
  return f2bf(a) | (f2bf(b) << 16);
}

// Grouped conv as 64 x [256x512x2048] bf16-MFMA GEMM + per-channel stats.
// Block = (g, z-tile 64, m-tile 256), 256 threads = 4 waves, wave tile 64z x 64m.
// Per K-chunk (BK=32 = 2 input channels): pack weights -> issue ck+2 global
// prefetch -> row-gather (2x ds_read_b128, compile-time tap selects) ->
// LDS-barrier -> write bf16 tiles -> LDS-barrier -> 16 MFMA per wave.
// Writes raw conv output into d_out in FOLD layout: out[b][z][hp*4+oy][wp*4+ox].
__global__ __launch_bounds__(256, 2) void conv_mfma(
    const float* __restrict__ input,   // [32,128,64,64]
    const float* __restrict__ weight,  // [16384, 2048]  (k = nc*16 + ky*4 + kx)
    float* __restrict__ out,           // [32,256,32,32]
    float* __restrict__ stats)         // [16384][2] (sum, sumsq)
{
  // raw patch tiles: 32 patches (16 b x 2 nc) x 64 floats, row-XOR swizzle:
  //   addr(fl) = pl*64 + ((py ^ (bl&7))<<3) + px
  __shared__ __align__(16) float raw0[32 * 64];   // 8 KB
  __shared__ __align__(16) float raw1[32 * 64];   // 8 KB
  // GEMM tiles, row = 64B (32 bf16), 16B-granule XOR swizzle (gk ^ ((row>>1)&3))
  __shared__ __align__(16) char Bs[256 * 64];     // 16 KB
  __shared__ __align__(16) char As[64 * 64];      // 4 KB

  const int bid  = blockIdx.x;
  const int orig = (bid & 7) * 64 + (bid >> 3);   // XCD-chunked (512 % 8 == 0)
  const int g    = orig >> 3;
  const int zt   = (orig >> 1) & 3;
  const int mt   = orig & 1;
  const int hp = g >> 3, wp = g & 7;
  const int z0 = zt * 64;
  const int m0 = mt * 256;

  const int tid  = threadIdx.x;
  const int lane = tid & 63;
  const int w    = tid >> 6;                      // wave 0..3, m-range = m0 + w*64
  const int llo  = lane & 15, lhi = lane >> 4;

  // -------- raw staging: thread -> patch pl=tid>>3, f4=tid&7 (rows 0-3 / 4-7)
  const int pl_s = tid >> 3;
  const int f4   = tid & 7;
  const int bl_s = pl_s >> 1;
  const int ncs_s = pl_s & 1;
  const int py_s = f4 >> 1, h_s = f4 & 1;
  const float* const gsrc = input
      + ((size_t)(mt * 16 + bl_s) * 128 + ncs_s) * 4096
      + (hp * 8 + py_s) * 64 + wp * 8 + (h_s << 2);   // 2nd load: +256 floats (py+4)
  const int roffA = pl_s * 64 + ((py_s ^ (bl_s & 7)) << 3) + (h_s << 2);
  const int roffB = pl_s * 64 + (((py_s + 4) ^ (bl_s & 7)) << 3) + (h_s << 2);
  float* const rd0a = raw0 + roffA;  float* const rd0b = raw0 + roffB;
  float* const rd1a = raw1 + roffA;  float* const rd1b = raw1 + roffB;

  // -------- weight staging: rows az0=tid>>3 and az0+32; kq=tid&7 (k=kq*4..+3)
  const int az0 = tid >> 3;
  const int kq  = tid & 7;
  const float* const wsrc =
      weight + ((size_t)(g * 256 + z0 + az0)) * 2048 + kq * 4;  // 2nd: +65536
  const int aswz = (az0 >> 1) & 3;   // ((az0+32)>>1)&3 is identical
  char* const ad0 = As + az0 * 64 + (((kq >> 1) ^ aswz) << 4) + ((kq & 1) << 3);
  char* const ad1 = ad0 + 32 * 64;

  // -------- row-gather: thread -> (bl=tid>>4, oy=(tid>>2)&3, ky=tid&3)
  const int bl_g = tid >> 4;
  const int oy_g = (tid >> 2) & 3;
  const int ky_g = tid & 3;
  const int iy   = 2 * oy_g - 1 + ky_g;
  const unsigned rowm = ((unsigned)iy < 8u) ? 0xFFFFFFFFu : 0u;
  const int iyc  = iy < 0 ? 0 : (iy > 7 ? 7 : iy);
  const int swzg = bl_g & 7;
  const int gro0 = (bl_g * 2 + 0) * 64 + ((iyc ^ swzg) << 3);
  const int gro1 = (bl_g * 2 + 1) * 64 + ((iyc ^ swzg) << 3);
  // B-write dsts: ml = bl*16+oy*4+ox, byte col = ncs*32 + ky*8
  char* bwd[2][4];
#pragma unroll
  for (int ncs = 0; ncs < 2; ++ncs)
#pragma unroll
    for (int ox = 0; ox < 4; ++ox) {
      const int ml = bl_g * 16 + oy_g * 4 + ox;
      const int gk = ncs * 2 + (ky_g >> 1);
      bwd[ncs][ox] = Bs + ml * 64 + ((gk ^ ((ml >> 1) & 3)) << 4) + ((ky_g & 1) << 3);
    }

  // -------- fragment read pointers
  const char* afp[4];
#pragma unroll
  for (int zf = 0; zf < 4; ++zf) {
    const int ar = zf * 16 + llo;
    afp[zf] = As + ar * 64 + ((lhi ^ ((ar >> 1) & 3)) << 4);
  }
  const char* bfp[4];
#pragma unroll
  for (int mf = 0; mf < 4; ++mf) {
    const int mr = w * 64 + mf * 16 + llo;
    bfp[mf] = Bs + mr * 64 + ((lhi ^ ((mr >> 1) & 3)) << 4);
  }

  f32x4 acc[4][4] = {};

  // tap selects: row[0..7] = r0.xyzw r1.xyzw; tap(ox,kx) = row[2ox-1+kx]
  uint2 ub[2][4];
  auto gather = [&](const float* rw) {
#pragma unroll
    for (int ncs = 0; ncs < 2; ++ncs) {
      const int gro = ncs ? gro1 : gro0;
      const float4 r0 = *(const float4*)(rw + gro);
      const float4 r1 = *(const float4*)(rw + gro + 4);
      uint2 t;
      t.x = packbf(0.f, r0.x) & rowm;  t.y = packbf(r0.y, r0.z) & rowm;  ub[ncs][0] = t;
      t.x = packbf(r0.y, r0.z) & rowm; t.y = packbf(r0.w, r1.x) & rowm;  ub[ncs][1] = t;
      t.x = packbf(r0.w, r1.x) & rowm; t.y = packbf(r1.y, r1.z) & rowm;  ub[ncs][2] = t;
      t.x = packbf(r1.y, r1.z) & rowm; t.y = packbf(r1.w, 0.f) & rowm;   ub[ncs][3] = t;
    }
  };
  auto writeB = [&]() {
#pragma unroll
    for (int ncs = 0; ncs < 2; ++ncs)
#pragma unroll
      for (int ox = 0; ox < 4; ++ox) *(uint2*)bwd[ncs][ox] = ub[ncs][ox];
  };
  auto domfma = [&]() {
    bf16x8 bfv[4];
#pragma unroll
    for (int mf = 0; mf < 4; ++mf) bfv[mf] = *(const bf16x8*)bfp[mf];
#pragma unroll
    for (int zf = 0; zf < 4; ++zf) {
      const bf16x8 af = *(const bf16x8*)afp[zf];
#pragma unroll
      for (int mf = 0; mf < 4; ++mf)
        acc[zf][mf] = __builtin_amdgcn_mfma_f32_16x16x32_bf16(af, bfv[mf], acc[zf][mf], 0, 0, 0);
    }
  };

  // -------- prologue: prefetch chunks 0,1; stage chunk 0 into raw0
  float4 ra0 = *(const float4*)(gsrc);
  float4 ra1 = *(const float4*)(gsrc + 256);
  float4 rb0 = *(const float4*)(gsrc + 8192);
  float4 rb1 = *(const float4*)(gsrc + 8192 + 256);
  float4 wa0 = *(const float4*)(wsrc);
  float4 wa1 = *(const float4*)(wsrc + 65536);
  float4 wb0 = *(const float4*)(wsrc + 32);
  float4 wb1 = *(const float4*)(wsrc + 65536 + 32);
  *(float4*)rd0a = ra0;
  *(float4*)rd0b = ra1;
  LDS_BARRIER();

  for (int ck = 0; ck < 64; ck += 2) {
    // ============ even chunk ck (gather raw0, stage ck+1 -> raw1) ============
    {
      // pack current weights first, then reuse regs for ck+2 prefetch
      uint2 a0w, a1w;
      a0w.x = packbf(wa0.x, wa0.y); a0w.y = packbf(wa0.z, wa0.w);
      a1w.x = packbf(wa1.x, wa1.y); a1w.y = packbf(wa1.z, wa1.w);
      if (ck + 2 < 64) {
        ra0 = *(const float4*)(gsrc + (size_t)(ck + 2) * 8192);
        ra1 = *(const float4*)(gsrc + (size_t)(ck + 2) * 8192 + 256);
        wa0 = *(const float4*)(wsrc + (ck + 2) * 32);
        wa1 = *(const float4*)(wsrc + 65536 + (ck + 2) * 32);
      }
      gather(raw0);
      LDS_BARRIER();               // prev MFMAs + this gather done reading LDS
      *(uint2*)ad0 = a0w;
      *(uint2*)ad1 = a1w;
      writeB();
      *(float4*)rd1a = rb0;        // stage chunk ck+1 (loaded 2 phases ago)
      *(float4*)rd1b = rb1;
      LDS_BARRIER();               // tiles + raw1 visible
      domfma();
    }
    // ============ odd chunk ck+1 (gather raw1, stage ck+2 -> raw0) ===========
    {
      uint2 a0w, a1w;
      a0w.x = packbf(wb0.x, wb0.y); a0w.y = packbf(wb0.z, wb0.w);
      a1w.x = packbf(wb1.x, wb1.y); a1w.y = packbf(wb1.z, wb1.w);
      if (ck + 3 < 64) {
        rb0 = *(const float4*)(gsrc + (size_t)(ck + 3) * 8192);
        rb1 = *(const float4*)(gsrc + (size_t)(ck + 3) * 8192 + 256);
        wb0 = *(const float4*)(wsrc + (ck + 3) * 32);
        wb1 = *(const float4*)(wsrc + 65536 + (ck + 3) * 32);
      }
      gather(raw1);
      LDS_BARRIER();
      *(uint2*)ad0 = a0w;
      *(uint2*)ad1 = a1w;
      writeB();
      if (ck + 2 < 64) { *(float4*)rd0a = ra0; *(float4*)rd0b = ra1; }
      LDS_BARRIER();
      domfma();
    }
  }

  // -------- per-channel stats (sum, sumsq) over the wave's 64 m
#pragma unroll
  for (int zf = 0; zf < 4; ++zf) {
    float s[4], ss[4];
#pragma unroll
    for (int r = 0; r < 4; ++r) {
      s[r]  = acc[zf][0][r] + acc[zf][1][r] + acc[zf][2][r] + acc[zf][3][r];
      ss[r] = acc[zf][0][r] * acc[zf][0][r] + acc[zf][1][r] * acc[zf][1][r]
            + acc[zf][2][r] * acc[zf][2][r] + acc[zf][3][r] * acc[zf][3][r];
    }
#pragma unroll
    for (int off = 1; off <= 8; off <<= 1) {
#pragma unroll
      for (int r = 0; r < 4; ++r) {
        s[r]  += __shfl_xor(s[r], off);
        ss[r] += __shfl_xor(ss[r], off);
      }
    }
    if (llo == 0) {
      const int ch = g * 256 + z0 + zf * 16 + lhi * 4;
#pragma unroll
      for (int r = 0; r < 4; ++r) {
        atomicAdd(&stats[2 * (ch + r)],     s[r]);
        atomicAdd(&stats[2 * (ch + r) + 1], ss[r]);
      }
    }
  }

  // -------- store raw conv to d_out in fold layout
#pragma unroll
  for (int zf = 0; zf < 4; ++zf) {
    const int zch = z0 + zf * 16 + lhi * 4;       // + r below
#pragma unroll
    for (int mf = 0; mf < 4; ++mf) {
      const int mm  = m0 + w * 64 + mf * 16 + llo;
      const int bb  = mm >> 4;
      const int o_y = (mm >> 2) & 3;
      const int o_x = mm & 3;
      float* op = out + (((size_t)bb * 256 + zch) * 32 + hp * 4 + o_y) * 32
                      + wp * 4 + o_x;
#pragma unroll
      for (int r = 0; r < 4; ++r) op[(size_t)r * 1024] = acc[zf][mf][r];
    }
  }
}

// Pass 2: in-place BatchNorm (batch stats) + LeakyReLU on the fold-layout buffer.
__global__ __launch_bounds__(256) void bn_lrelu(
    float* __restrict__ out,
    const float* __restrict__ stats,
    const float* __restrict__ gamma,
    const float* __restrict__ beta)
{
  size_t t = (size_t)blockIdx.x * blockDim.x + threadIdx.x;
  size_t o = t * 4;                    // float4 per thread
  int X0 = (int)(o & 31);
  int Y  = (int)((o >> 5) & 31);
  int z  = (int)((o >> 10) & 255);
  int ch = ((Y >> 2) * 8 + (X0 >> 2)) * 256 + z;  // (hp*8+wp)*256 + z
  float s  = stats[2 * ch];
  float ss = stats[2 * ch + 1];
  float mean = s * (1.f / 512.f);
  float var  = fmaf(-mean, mean, ss * (1.f / 512.f));
  float inv  = gamma[ch] * rsqrtf(var + kEps);
  float sh   = fmaf(-mean, inv, beta[ch]);
  float4 v = *(float4*)&out[o];
  float vv[4] = {v.x, v.y, v.z, v.w};
#pragma unroll
  for (int j = 0; j < 4; ++j) {
    float y = fmaf(vv[j], inv, sh);
    vv[j] = y > 0.f ? y : kLrelu * y;
  }
  *(float4*)&out[o] = make_float4(vv[0], vv[1], vv[2], vv[3]);
}

extern "C" void kernel_launch(void* const* d_in, const int* in_sizes, int n_in,
                              void* d_out, int out_size, void* d_ws, size_t ws_size,
                              hipStream_t stream) {
  const float* input  = (const float*)d_in[0];
  const float* weight = (const float*)d_in[1];
  const float* gamma  = (const float*)d_in[2];
  const float* beta   = (const float*)d_in[3];
  float* out   = (float*)d_out;
  float* stats = (float*)d_ws;  // 16384 * 2 floats = 128 KB

  (void)hipMemsetAsync(stats, 0, (size_t)16384 * 2 * sizeof(float), stream);

  conv_mfma<<<512, 256, 0, stream>>>(input, weight, out, stats);

  int n4 = out_size / 4;               // 2,097,152 float4s
  bn_lrelu<<<(n4 + 255) / 256, 256, 0, stream>>>(out, stats, gamma, beta);
}